// Round 7
// baseline (638.510 us; speedup 1.0000x reference)
//
#include <hip/hip_runtime.h>
#include <hip/hip_bf16.h>
#include <cmath>

// Problem constants (fixed by setup_inputs)
constexpr int S = 128;   // num_states
constexpr int C = 32;    // num_chains
constexpr int N = 4096;  // num_nodes
constexpr int T = 512;   // num_iters

// Output layout (flat float32, concatenated in reference return order)
constexpr size_t OFF1 = 0;                          // log_observed_state_probs  [T,N]
constexpr size_t OFF2 = OFF1 + (size_t)T * N;       // log_observed_state_probs_ [T,C,N]
constexpr size_t OFF3 = OFF2 + (size_t)T * C * N;   // log_hidden_state_probs   [T,C,S]
constexpr size_t OFF4 = OFF3 + (size_t)T * C * S;   // log_emission             [S,N]
constexpr size_t OFF5 = OFF4 + (size_t)S * N;       // log_chain_weights        [T,C]

constexpr int PP = S * S;          // 16384 elems per P plane
typedef __bf16 bf16x8 __attribute__((ext_vector_type(8)));
typedef float floatx4 __attribute__((ext_vector_type(4)));
typedef float floatx16 __attribute__((ext_vector_type(16)));

__device__ __forceinline__ void split_bf16(float p, __bf16& hi, __bf16& lo) {
    hi = (__bf16)p;
    lo = (__bf16)(p - (float)hi);
}

// ---------------------------------------------------------------------------
// Fused softmax kernel (unchanged math). Transition writes P^1: R pair +
// T pair (T pair goes directly into Tpow table slot 0).
// ---------------------------------------------------------------------------
__global__ __launch_bounds__(256) void fused_softmax_kernel(
        const float* __restrict__ emis, const float* __restrict__ cw,
        const float* __restrict__ trans, const float* __restrict__ init,
        float* __restrict__ out3, float* __restrict__ out4, float* __restrict__ out5,
        __bf16* __restrict__ pET, float* __restrict__ pcw,
        __bf16* __restrict__ R1hi, __bf16* __restrict__ R1lo,
        __bf16* __restrict__ Tpow,     // slot 0: [hi 16384][lo 16384]
        __bf16* __restrict__ Hhi, __bf16* __restrict__ Hlo) {
    const int b = blockIdx.x;
    const int tid = threadIdx.x;

    if (b >= 288) {   // ---- chain weights: 8 rows of 32 per block ----
        const int row = (b - 288) * 8 + (tid >> 5);
        const int j = tid & 31;
        const float v = cw[(size_t)row * C + j];
        float m = v;
#pragma unroll
        for (int o = 16; o > 0; o >>= 1) m = fmaxf(m, __shfl_xor(m, o, 64));
        float s = __expf(v - m);
#pragma unroll
        for (int o = 16; o > 0; o >>= 1) s += __shfl_xor(s, o, 64);
        const float lv = v - m - __logf(s);
        out5[(size_t)row * C + j] = lv;
        pcw[(size_t)row * C + j] = __expf(lv);
        return;
    }

    const float* x;
    int cols, row;
    if (b < 128)      { row = b;       cols = N; x = emis  + (size_t)row * N; }
    else if (b < 256) { row = b - 128; cols = S; x = trans + (size_t)row * S; }
    else              { row = b - 256; cols = S; x = init  + (size_t)row * S; }

    __shared__ float sm[4];
    __shared__ float ss[4];

    float m = -INFINITY;
    for (int j = tid; j < cols; j += 256) m = fmaxf(m, x[j]);
#pragma unroll
    for (int o = 32; o > 0; o >>= 1) m = fmaxf(m, __shfl_xor(m, o, 64));
    const int wid = tid >> 6;
    if ((tid & 63) == 0) sm[wid] = m;
    __syncthreads();
    m = fmaxf(fmaxf(sm[0], sm[1]), fmaxf(sm[2], sm[3]));

    float s = 0.f;
    for (int j = tid; j < cols; j += 256) s += __expf(x[j] - m);
#pragma unroll
    for (int o = 32; o > 0; o >>= 1) s += __shfl_xor(s, o, 64);
    if ((tid & 63) == 0) ss[wid] = s;
    __syncthreads();
    s = ss[0] + ss[1] + ss[2] + ss[3];
    const float lse = m + __logf(s);

    for (int j = tid; j < cols; j += 256) {
        const float v = x[j] - lse;
        const float p = __expf(v);
        if (b < 128) {
            out4[(size_t)row * N + j] = v;
            pET[(size_t)j * S + row] = (__bf16)p;
        } else if (b < 256) {
            __bf16 hi, lo; split_bf16(p, hi, lo);
            R1hi[(size_t)row * S + j] = hi; R1lo[(size_t)row * S + j] = lo;
            Tpow[(size_t)j * S + row] = hi; Tpow[PP + (size_t)j * S + row] = lo;
        } else {
            out3[((size_t)0 * C + row) * S + j] = v;
            __bf16 hi, lo; split_bf16(p, hi, lo);
            Hhi[(size_t)row * S + j] = hi; Hlo[(size_t)row * S + j] = lo;
        }
    }
}

// ---------------------------------------------------------------------------
// P-power kernel: ONE block, 512 threads. All 8 squarings P^2..P^256 done
// with R,T hi/lo pairs LDS-resident (128 KB); results register-staged across
// a barrier (no LDS double-buffer, no global RAW). Writes T-layout pair of
// P^(2^s) to Tpow slot s.
// ---------------------------------------------------------------------------
__global__ __launch_bounds__(512) void ppow_kernel(
        const __bf16* __restrict__ R1hi, const __bf16* __restrict__ R1lo,
        __bf16* __restrict__ Tpow) {    // [9 slots][hi PP][lo PP]
    __shared__ __bf16 Rh[PP], Rl[PP], Th[PP], Tl[PP];   // 128 KB
    const int tid = threadIdx.x;

    // Load P^1 (R pair from R1*, T pair from Tpow slot 0)
    for (int ch = tid; ch < PP / 8; ch += 512) {
        *reinterpret_cast<bf16x8*>(&Rh[ch * 8]) = *reinterpret_cast<const bf16x8*>(&R1hi[ch * 8]);
        *reinterpret_cast<bf16x8*>(&Rl[ch * 8]) = *reinterpret_cast<const bf16x8*>(&R1lo[ch * 8]);
        *reinterpret_cast<bf16x8*>(&Th[ch * 8]) = *reinterpret_cast<const bf16x8*>(&Tpow[ch * 8]);
        *reinterpret_cast<bf16x8*>(&Tl[ch * 8]) = *reinterpret_cast<const bf16x8*>(&Tpow[PP + ch * 8]);
    }
    __syncthreads();

    const int w = tid >> 6;
    const int lane = tid & 63;
    const int l31 = lane & 31;
    const int half = lane >> 5;
    const int i = w >> 1;              // row-block 0..3
    const int j0 = (w & 1) * 2;        // col-blocks j0, j0+1

    for (int s = 1; s <= 8; s++) {
        floatx16 acc[2];
        acc[0] = (floatx16)0.f; acc[1] = (floatx16)0.f;
#pragma unroll
        for (int ks = 0; ks < 8; ks++) {
            const int ko = ks * 16 + half * 8;
            const bf16x8 ah = *reinterpret_cast<const bf16x8*>(&Rh[(32 * i + l31) * S + ko]);
            const bf16x8 al = *reinterpret_cast<const bf16x8*>(&Rl[(32 * i + l31) * S + ko]);
            const bf16x8 bh0 = *reinterpret_cast<const bf16x8*>(&Th[(32 * j0 + l31) * S + ko]);
            const bf16x8 bl0 = *reinterpret_cast<const bf16x8*>(&Tl[(32 * j0 + l31) * S + ko]);
            const bf16x8 bh1 = *reinterpret_cast<const bf16x8*>(&Th[(32 * (j0 + 1) + l31) * S + ko]);
            const bf16x8 bl1 = *reinterpret_cast<const bf16x8*>(&Tl[(32 * (j0 + 1) + l31) * S + ko]);
            acc[0] = __builtin_amdgcn_mfma_f32_32x32x16_bf16(ah, bh0, acc[0], 0, 0, 0);
            acc[0] = __builtin_amdgcn_mfma_f32_32x32x16_bf16(ah, bl0, acc[0], 0, 0, 0);
            acc[0] = __builtin_amdgcn_mfma_f32_32x32x16_bf16(al, bh0, acc[0], 0, 0, 0);
            acc[1] = __builtin_amdgcn_mfma_f32_32x32x16_bf16(ah, bh1, acc[1], 0, 0, 0);
            acc[1] = __builtin_amdgcn_mfma_f32_32x32x16_bf16(ah, bl1, acc[1], 0, 0, 0);
            acc[1] = __builtin_amdgcn_mfma_f32_32x32x16_bf16(al, bh1, acc[1], 0, 0, 0);
        }
        __syncthreads();   // all reads of P^m done; safe to overwrite LDS
#pragma unroll
        for (int jj = 0; jj < 2; jj++) {
#pragma unroll
            for (int reg = 0; reg < 16; reg++) {
                const int crow = (reg & 3) + 8 * (reg >> 2) + 4 * half;
                const int gr = 32 * i + crow;
                const int gc = 32 * (j0 + jj) + l31;
                __bf16 hi, lo; split_bf16(acc[jj][reg], hi, lo);
                Rh[gr * S + gc] = hi; Rl[gr * S + gc] = lo;
                Th[gc * S + gr] = hi; Tl[gc * S + gr] = lo;
                Tpow[(size_t)s * 2 * PP + gc * S + gr] = hi;
                Tpow[(size_t)s * 2 * PP + PP + gc * S + gr] = lo;
            }
        }
        __syncthreads();
    }
}

// ---------------------------------------------------------------------------
// Fused H-rounds 1..4: ONE block, 512 threads. H_0..H_7 hi/lo LDS-resident
// (128 KB) -> all intra-kernel RAW goes through LDS (no global RAW). B from
// precomputed Tpow tables (written by ppow, prior dispatch - safe). Writes
// H_1..H_15 pair + log -> out3.
// ---------------------------------------------------------------------------
__global__ __launch_bounds__(512) void hfuse_kernel(
        const __bf16* __restrict__ Tpow,
        __bf16* __restrict__ Hhi, __bf16* __restrict__ Hlo,
        float* __restrict__ out3) {
    __shared__ __bf16 Hs[2 * 8 * C * S];   // [plane][t<8][c][s], 128 KB
    const int tid = threadIdx.x;

    for (int ch = tid; ch < (C * S) / 8; ch += 512) {
        *reinterpret_cast<bf16x8*>(&Hs[ch * 8]) = *reinterpret_cast<const bf16x8*>(&Hhi[ch * 8]);
        *reinterpret_cast<bf16x8*>(&Hs[8 * C * S + ch * 8]) = *reinterpret_cast<const bf16x8*>(&Hlo[ch * 8]);
    }
    __syncthreads();

    const int sub = tid >> 8;          // two 256-thread tile groups
    const int t256 = tid & 255;
    const int w = t256 >> 6;
    const int lane = t256 & 63;
    const int lr = lane & 15;
    const int quad = lane >> 4;

    for (int r = 1; r <= 4; r++) {
        const int m = 1 << (r - 1);
        const __bf16* Th = Tpow + (size_t)(r - 1) * 2 * PP;
        const __bf16* Tl = Th + PP;
        for (int b = sub; b < m; b += 2) {
            const __bf16* Ahi = Hs + b * C * S;
            const __bf16* Alo = Hs + 8 * C * S + b * C * S;
            floatx4 acc[2][2];
#pragma unroll
            for (int mt = 0; mt < 2; mt++)
#pragma unroll
                for (int nt = 0; nt < 2; nt++) acc[mt][nt] = (floatx4)0.f;
#pragma unroll
            for (int kt = 0; kt < 4; kt++) {
                const int ko = kt * 32 + quad * 8;
                const bf16x8 ah0 = *reinterpret_cast<const bf16x8*>(&Ahi[lr * S + ko]);
                const bf16x8 ah1 = *reinterpret_cast<const bf16x8*>(&Ahi[(16 + lr) * S + ko]);
                const bf16x8 al0 = *reinterpret_cast<const bf16x8*>(&Alo[lr * S + ko]);
                const bf16x8 al1 = *reinterpret_cast<const bf16x8*>(&Alo[(16 + lr) * S + ko]);
                const bf16x8 bh0 = *reinterpret_cast<const bf16x8*>(&Th[(w * 32 + lr) * S + ko]);
                const bf16x8 bh1 = *reinterpret_cast<const bf16x8*>(&Th[(w * 32 + 16 + lr) * S + ko]);
                const bf16x8 bl0 = *reinterpret_cast<const bf16x8*>(&Tl[(w * 32 + lr) * S + ko]);
                const bf16x8 bl1 = *reinterpret_cast<const bf16x8*>(&Tl[(w * 32 + 16 + lr) * S + ko]);
                acc[0][0] = __builtin_amdgcn_mfma_f32_16x16x32_bf16(ah0, bh0, acc[0][0], 0, 0, 0);
                acc[0][0] = __builtin_amdgcn_mfma_f32_16x16x32_bf16(ah0, bl0, acc[0][0], 0, 0, 0);
                acc[0][0] = __builtin_amdgcn_mfma_f32_16x16x32_bf16(al0, bh0, acc[0][0], 0, 0, 0);
                acc[0][1] = __builtin_amdgcn_mfma_f32_16x16x32_bf16(ah0, bh1, acc[0][1], 0, 0, 0);
                acc[0][1] = __builtin_amdgcn_mfma_f32_16x16x32_bf16(ah0, bl1, acc[0][1], 0, 0, 0);
                acc[0][1] = __builtin_amdgcn_mfma_f32_16x16x32_bf16(al0, bh1, acc[0][1], 0, 0, 0);
                acc[1][0] = __builtin_amdgcn_mfma_f32_16x16x32_bf16(ah1, bh0, acc[1][0], 0, 0, 0);
                acc[1][0] = __builtin_amdgcn_mfma_f32_16x16x32_bf16(ah1, bl0, acc[1][0], 0, 0, 0);
                acc[1][0] = __builtin_amdgcn_mfma_f32_16x16x32_bf16(al1, bh0, acc[1][0], 0, 0, 0);
                acc[1][1] = __builtin_amdgcn_mfma_f32_16x16x32_bf16(ah1, bh1, acc[1][1], 0, 0, 0);
                acc[1][1] = __builtin_amdgcn_mfma_f32_16x16x32_bf16(ah1, bl1, acc[1][1], 0, 0, 0);
                acc[1][1] = __builtin_amdgcn_mfma_f32_16x16x32_bf16(al1, bh1, acc[1][1], 0, 0, 0);
            }
            const int t = m + b;
#pragma unroll
            for (int mt = 0; mt < 2; mt++) {
#pragma unroll
                for (int nt = 0; nt < 2; nt++) {
#pragma unroll
                    for (int reg = 0; reg < 4; reg++) {
                        const int c = mt * 16 + quad * 4 + reg;
                        const int n = w * 32 + nt * 16 + lr;
                        const float p = acc[mt][nt][reg];
                        __bf16 hi, lo; split_bf16(p, hi, lo);
                        Hhi[((size_t)t * C + c) * S + n] = hi;
                        Hlo[((size_t)t * C + c) * S + n] = lo;
                        out3[((size_t)t * C + c) * S + n] = __logf(p);
                        if (t < 8) {
                            Hs[t * C * S + c * S + n] = hi;
                            Hs[8 * C * S + t * C * S + c * S + n] = lo;
                        }
                    }
                }
            }
        }
        __syncthreads();
    }
}

// ---------------------------------------------------------------------------
// H-round tail (r = 5..9): pure parallel H_{m+b} = H_b * P^m, B from Tpow.
// No squaring riders anymore.
// ---------------------------------------------------------------------------
__global__ __launch_bounds__(256) void h_tail_kernel(
        const __bf16* __restrict__ Th, const __bf16* __restrict__ Tl,
        __bf16* __restrict__ Hhi, __bf16* __restrict__ Hlo,
        float* __restrict__ out3, int m) {
    const int b = blockIdx.x;
    const int w = threadIdx.x >> 6;
    const int lane = threadIdx.x & 63;
    const int lr = lane & 15;
    const int quad = lane >> 4;

    const __bf16* Ahi = Hhi + (size_t)b * C * S;
    const __bf16* Alo = Hlo + (size_t)b * C * S;
    floatx4 acc[2][2];
#pragma unroll
    for (int mt = 0; mt < 2; mt++)
#pragma unroll
        for (int nt = 0; nt < 2; nt++) acc[mt][nt] = (floatx4)0.f;

#pragma unroll
    for (int kt = 0; kt < 4; kt++) {
        const int ko = kt * 32 + quad * 8;
        const bf16x8 ah0 = *reinterpret_cast<const bf16x8*>(&Ahi[lr * S + ko]);
        const bf16x8 ah1 = *reinterpret_cast<const bf16x8*>(&Ahi[(16 + lr) * S + ko]);
        const bf16x8 al0 = *reinterpret_cast<const bf16x8*>(&Alo[lr * S + ko]);
        const bf16x8 al1 = *reinterpret_cast<const bf16x8*>(&Alo[(16 + lr) * S + ko]);
        const bf16x8 bh0 = *reinterpret_cast<const bf16x8*>(&Th[(w * 32 + lr) * S + ko]);
        const bf16x8 bh1 = *reinterpret_cast<const bf16x8*>(&Th[(w * 32 + 16 + lr) * S + ko]);
        const bf16x8 bl0 = *reinterpret_cast<const bf16x8*>(&Tl[(w * 32 + lr) * S + ko]);
        const bf16x8 bl1 = *reinterpret_cast<const bf16x8*>(&Tl[(w * 32 + 16 + lr) * S + ko]);
        acc[0][0] = __builtin_amdgcn_mfma_f32_16x16x32_bf16(ah0, bh0, acc[0][0], 0, 0, 0);
        acc[0][0] = __builtin_amdgcn_mfma_f32_16x16x32_bf16(ah0, bl0, acc[0][0], 0, 0, 0);
        acc[0][0] = __builtin_amdgcn_mfma_f32_16x16x32_bf16(al0, bh0, acc[0][0], 0, 0, 0);
        acc[0][1] = __builtin_amdgcn_mfma_f32_16x16x32_bf16(ah0, bh1, acc[0][1], 0, 0, 0);
        acc[0][1] = __builtin_amdgcn_mfma_f32_16x16x32_bf16(ah0, bl1, acc[0][1], 0, 0, 0);
        acc[0][1] = __builtin_amdgcn_mfma_f32_16x16x32_bf16(al0, bh1, acc[0][1], 0, 0, 0);
        acc[1][0] = __builtin_amdgcn_mfma_f32_16x16x32_bf16(ah1, bh0, acc[1][0], 0, 0, 0);
        acc[1][0] = __builtin_amdgcn_mfma_f32_16x16x32_bf16(ah1, bl0, acc[1][0], 0, 0, 0);
        acc[1][0] = __builtin_amdgcn_mfma_f32_16x16x32_bf16(al1, bh0, acc[1][0], 0, 0, 0);
        acc[1][1] = __builtin_amdgcn_mfma_f32_16x16x32_bf16(ah1, bh1, acc[1][1], 0, 0, 0);
        acc[1][1] = __builtin_amdgcn_mfma_f32_16x16x32_bf16(ah1, bl1, acc[1][1], 0, 0, 0);
        acc[1][1] = __builtin_amdgcn_mfma_f32_16x16x32_bf16(al1, bh1, acc[1][1], 0, 0, 0);
    }

    const size_t t = (size_t)m + b;
#pragma unroll
    for (int mt = 0; mt < 2; mt++) {
#pragma unroll
        for (int nt = 0; nt < 2; nt++) {
#pragma unroll
            for (int reg = 0; reg < 4; reg++) {
                const int c = mt * 16 + quad * 4 + reg;
                const int n = w * 32 + nt * 16 + lr;
                const float p = acc[mt][nt][reg];
                __bf16 hi, lo; split_bf16(p, hi, lo);
                Hhi[(t * C + c) * S + n] = hi;
                Hlo[(t * C + c) * S + n] = lo;
                out3[(t * C + c) * S + n] = __logf(p);
            }
        }
    }
}

// ---------------------------------------------------------------------------
// Observation GEMM (R6 math, unchanged) -- DIAGNOSTIC grid this round:
// 128 blocks each sweeping 16 t-batches so the dispatch exceeds the harness
// fill duration and surfaces full rocprof counters. Revert to grid (32,64)
// with a single sweep next round.
// ---------------------------------------------------------------------------
__global__ __launch_bounds__(512, 4) void obs_mfma_kernel(
        const __bf16* __restrict__ Hb,    // [T,C,S] (hi plane)
        const __bf16* __restrict__ pET,   // [N,S]
        const float* __restrict__ pcw,    // [T,C]
        float* __restrict__ out1,
        float* __restrict__ out2) {
    constexpr int BPITCH = 264;  // bytes per LDS row (256 data + 8 pad)
    __shared__ __align__(16) unsigned char Bs[128 * BPITCH];  // 33 KB
    __shared__ float sw[8][C];

    const int tid = threadIdx.x;
    const int w = tid >> 6;
    const int lane = tid & 63;
    const int l31 = lane & 31;
    const int half = lane >> 5;
    const int nw = (w & 1) * 64;
    const int tg = w >> 1;
    const int nblk = blockIdx.x * 128;

    // Stage pET rows once (depends only on nblk).
#pragma unroll
    for (int p = 0; p < 4; p++) {
        const int idx = p * 512 + tid;
        const int row = idx >> 4;
        const int c16 = idx & 15;
        const float4 v = *reinterpret_cast<const float4*>(
            pET + (size_t)(nblk + row) * S + c16 * 8);
        *reinterpret_cast<float4*>(Bs + row * BPITCH + c16 * 16) = v;
    }

    for (int yk = 0; yk < 16; yk++) {
        const int tbase = (blockIdx.y + 4 * yk) * 8;
        if (tid < 256) sw[tid >> 5][tid & 31] =
            pcw[(size_t)(tbase + (tid >> 5)) * C + (tid & 31)];
        __syncthreads();

        const int t0 = tbase + tg * 2;
        const int t1 = t0 + 1;
        const __bf16* A0 = Hb + (size_t)t0 * C * S;
        const __bf16* A1 = Hb + (size_t)t1 * C * S;

        floatx16 acc[2][2];
#pragma unroll
        for (int tt = 0; tt < 2; tt++)
#pragma unroll
            for (int nt = 0; nt < 2; nt++) acc[tt][nt] = (floatx16)0.f;

#pragma unroll
        for (int ks = 0; ks < 8; ks++) {
            const int ko = ks * 16 + half * 8;
            const bf16x8 a0 = *reinterpret_cast<const bf16x8*>(&A0[(size_t)l31 * S + ko]);
            const bf16x8 a1 = *reinterpret_cast<const bf16x8*>(&A1[(size_t)l31 * S + ko]);
            const bf16x8 b0 = *reinterpret_cast<const bf16x8*>(Bs + (nw + l31) * BPITCH + ko * 2);
            const bf16x8 b1 = *reinterpret_cast<const bf16x8*>(Bs + (nw + 32 + l31) * BPITCH + ko * 2);
            acc[0][0] = __builtin_amdgcn_mfma_f32_32x32x16_bf16(a0, b0, acc[0][0], 0, 0, 0);
            acc[0][1] = __builtin_amdgcn_mfma_f32_32x32x16_bf16(a0, b1, acc[0][1], 0, 0, 0);
            acc[1][0] = __builtin_amdgcn_mfma_f32_32x32x16_bf16(a1, b0, acc[1][0], 0, 0, 0);
            acc[1][1] = __builtin_amdgcn_mfma_f32_32x32x16_bf16(a1, b1, acc[1][1], 0, 0, 0);
        }

#pragma unroll
        for (int tt = 0; tt < 2; tt++) {
            const int t = t0 + tt;
            float p0 = 0.f, p1 = 0.f;
#pragma unroll
            for (int reg = 0; reg < 16; reg++) {
                const int c = (reg & 3) + 8 * (reg >> 2) + 4 * half;
                const float o0 = acc[tt][0][reg];
                const float o1 = acc[tt][1][reg];
                __builtin_nontemporal_store(__logf(o0),
                    &out2[((size_t)t * C + c) * N + nblk + nw + l31]);
                __builtin_nontemporal_store(__logf(o1),
                    &out2[((size_t)t * C + c) * N + nblk + nw + 32 + l31]);
                p0 = fmaf(sw[tg * 2 + tt][c], o0, p0);
                p1 = fmaf(sw[tg * 2 + tt][c], o1, p1);
            }
            p0 += __shfl_xor(p0, 32, 64);
            p1 += __shfl_xor(p1, 32, 64);
            if (half == 0) {
                __builtin_nontemporal_store(__logf(p0), &out1[(size_t)t * N + nblk + nw + l31]);
                __builtin_nontemporal_store(__logf(p1), &out1[(size_t)t * N + nblk + nw + 32 + l31]);
            }
        }
        __syncthreads();   // sw reused next sweep
    }
}

// ---------------------------------------------------------------------------
extern "C" void kernel_launch(void* const* d_in, const int* in_sizes, int n_in,
                              void* d_out, int out_size, void* d_ws, size_t ws_size,
                              hipStream_t stream) {
    const float* in_init  = (const float*)d_in[0];  // [C,S]
    const float* in_cw    = (const float*)d_in[1];  // [T,C]
    const float* in_emis  = (const float*)d_in[2];  // [S,N]
    const float* in_trans = (const float*)d_in[3];  // [S,S]

    float* out = (float*)d_out;

    // Workspace layout (~9.7 MB, 256B aligned)
    char* wsb = (char*)d_ws;
    float*  ws_pcw = (float*)(wsb);                    // 64 KB [T,C]
    __bf16* ws_pET = (__bf16*)(wsb + (64u << 10));     // 1 MB  [N,S]
    __bf16* ws_Hhi = (__bf16*)(wsb + (1088u << 10));   // 4 MB  [T,C,S]
    __bf16* ws_Hlo = (__bf16*)(wsb + (5184u << 10));   // 4 MB  [T,C,S]
    __bf16* ws_R1hi = (__bf16*)(wsb + (9280u << 10));  // 32 KB
    __bf16* ws_R1lo = (__bf16*)(wsb + (9312u << 10));  // 32 KB
    __bf16* ws_Tpow = (__bf16*)(wsb + (9344u << 10));  // 9 x 64 KB T-layout pair tables

    // 1) All softmaxes in one launch (P^1 T pair -> Tpow slot 0).
    fused_softmax_kernel<<<352, 256, 0, stream>>>(
        in_emis, in_cw, in_trans, in_init,
        out + OFF3, out + OFF4, out + OFF5,
        ws_pET, ws_pcw, ws_R1hi, ws_R1lo, ws_Tpow, ws_Hhi, ws_Hlo);

    // 2) All squarings P^2..P^256 in one single-block LDS-resident kernel.
    ppow_kernel<<<1, 512, 0, stream>>>(ws_R1hi, ws_R1lo, ws_Tpow);

    // 3) H-rounds 1..4 fused in one single-block kernel (H_0..H_7 in LDS).
    hfuse_kernel<<<1, 512, 0, stream>>>(ws_Tpow, ws_Hhi, ws_Hlo, out + OFF3);

    // 4) H-rounds 5..9 (pure parallel, tables precomputed).
    for (int r = 5; r <= 9; r++) {
        const int m = 1 << (r - 1);
        const __bf16* Th = ws_Tpow + (size_t)(r - 1) * 2 * PP;
        h_tail_kernel<<<m, 256, 0, stream>>>(Th, Th + PP, ws_Hhi, ws_Hlo,
                                             out + OFF3, m);
    }

    // 5) Observation GEMM — diagnostic grid (32,4) x 16 sweeps this round.
    obs_mfma_kernel<<<dim3(N / 128, 4), 512, 0, stream>>>(
        ws_Hhi, ws_pET, ws_pcw, out + OFF1, out + OFF2);
}

// Round 8
// 377.696 us; speedup vs baseline: 1.6905x; 1.6905x over previous
//
#include <hip/hip_runtime.h>
#include <hip/hip_bf16.h>
#include <cmath>

// Problem constants (fixed by setup_inputs)
constexpr int S = 128;   // num_states
constexpr int C = 32;    // num_chains
constexpr int N = 4096;  // num_nodes
constexpr int T = 512;   // num_iters

// Output layout (flat float32, concatenated in reference return order)
constexpr size_t OFF1 = 0;                          // log_observed_state_probs  [T,N]
constexpr size_t OFF2 = OFF1 + (size_t)T * N;       // log_observed_state_probs_ [T,C,N]
constexpr size_t OFF3 = OFF2 + (size_t)T * C * N;   // log_hidden_state_probs   [T,C,S]
constexpr size_t OFF4 = OFF3 + (size_t)T * C * S;   // log_emission             [S,N]
constexpr size_t OFF5 = OFF4 + (size_t)S * N;       // log_chain_weights        [T,C]

typedef __bf16 bf16x8 __attribute__((ext_vector_type(8)));
typedef float floatx4 __attribute__((ext_vector_type(4)));
typedef float floatx16 __attribute__((ext_vector_type(16)));

__device__ __forceinline__ void split_bf16(float p, __bf16& hi, __bf16& lo) {
    hi = (__bf16)p;
    lo = (__bf16)(p - (float)hi);
}

// ---------------------------------------------------------------------------
// Fused softmax kernel, one launch, 352 blocks x 256 threads.
//   [0,128)   emission rows: log->out4, bf16 transposed -> pET[N,S]
//   [128,256) transition rows: hi/lo pair row-major (R) + transposed (T)
//   [256,288) init rows: log->out3[t=0], hi/lo pair -> Hhi/Hlo[t=0]
//   [288,352) chain weights (8 rows/block): log->out5, fp32 -> pcw
// ---------------------------------------------------------------------------
__global__ __launch_bounds__(256) void fused_softmax_kernel(
        const float* __restrict__ emis, const float* __restrict__ cw,
        const float* __restrict__ trans, const float* __restrict__ init,
        float* __restrict__ out3, float* __restrict__ out4, float* __restrict__ out5,
        __bf16* __restrict__ pET, float* __restrict__ pcw,
        __bf16* __restrict__ Rhi, __bf16* __restrict__ Rlo,
        __bf16* __restrict__ Thi, __bf16* __restrict__ Tlo,
        __bf16* __restrict__ Hhi, __bf16* __restrict__ Hlo) {
    const int b = blockIdx.x;
    const int tid = threadIdx.x;

    if (b >= 288) {   // ---- chain weights ----
        const int row = (b - 288) * 8 + (tid >> 5);
        const int j = tid & 31;
        const float v = cw[(size_t)row * C + j];
        float m = v;
#pragma unroll
        for (int o = 16; o > 0; o >>= 1) m = fmaxf(m, __shfl_xor(m, o, 64));
        float s = __expf(v - m);
#pragma unroll
        for (int o = 16; o > 0; o >>= 1) s += __shfl_xor(s, o, 64);
        const float lv = v - m - __logf(s);
        out5[(size_t)row * C + j] = lv;
        pcw[(size_t)row * C + j] = __expf(lv);
        return;
    }

    const float* x;
    int cols, row;
    if (b < 128)      { row = b;       cols = N; x = emis  + (size_t)row * N; }
    else if (b < 256) { row = b - 128; cols = S; x = trans + (size_t)row * S; }
    else              { row = b - 256; cols = S; x = init  + (size_t)row * S; }

    __shared__ float sm[4];
    __shared__ float ss[4];

    float m = -INFINITY;
    for (int j = tid; j < cols; j += 256) m = fmaxf(m, x[j]);
#pragma unroll
    for (int o = 32; o > 0; o >>= 1) m = fmaxf(m, __shfl_xor(m, o, 64));
    const int wid = tid >> 6;
    if ((tid & 63) == 0) sm[wid] = m;
    __syncthreads();
    m = fmaxf(fmaxf(sm[0], sm[1]), fmaxf(sm[2], sm[3]));

    float s = 0.f;
    for (int j = tid; j < cols; j += 256) s += __expf(x[j] - m);
#pragma unroll
    for (int o = 32; o > 0; o >>= 1) s += __shfl_xor(s, o, 64);
    if ((tid & 63) == 0) ss[wid] = s;
    __syncthreads();
    s = ss[0] + ss[1] + ss[2] + ss[3];
    const float lse = m + __logf(s);

    for (int j = tid; j < cols; j += 256) {
        const float v = x[j] - lse;
        const float p = __expf(v);
        if (b < 128) {
            out4[(size_t)row * N + j] = v;
            pET[(size_t)j * S + row] = (__bf16)p;
        } else if (b < 256) {
            __bf16 hi, lo; split_bf16(p, hi, lo);
            Rhi[(size_t)row * S + j] = hi; Rlo[(size_t)row * S + j] = lo;
            Thi[(size_t)j * S + row] = hi; Tlo[(size_t)j * S + row] = lo;
        } else {
            out3[((size_t)0 * C + row) * S + j] = v;
            __bf16 hi, lo; split_bf16(p, hi, lo);
            Hhi[(size_t)row * S + j] = hi; Hlo[(size_t)row * S + j] = lo;
        }
    }
}

// ---------------------------------------------------------------------------
// One H-doubling round (m = 2^(r-1)), hi/lo bf16 pair MFMA (3 MFMAs per
// product -> ~fp32 accuracy). [Proven ~42 us for all 9 launches. Cooperative
// grid.sync variant: 300 us. Single-block LDS-resident squaring chain:
// 182 us (32-way LDS bank conflicts on transposed writes). Keep THIS shape.]
//   blocks [0, count):       H_{m+b} = H_b * P^m   (+ pair store + log->out3)
//   blocks [count, count+8): P^{2m}  = P^m * P^m   (16 rows each, both layouts)
// store_lo=0 skips the Hlo store (valid when no later round consumes it).
// ---------------------------------------------------------------------------
__global__ __launch_bounds__(256) void h_round_kernel(
        const __bf16* __restrict__ Rhi, const __bf16* __restrict__ Rlo,
        const __bf16* __restrict__ Thi, const __bf16* __restrict__ Tlo,
        __bf16* __restrict__ Rnhi, __bf16* __restrict__ Rnlo,
        __bf16* __restrict__ Tnhi, __bf16* __restrict__ Tnlo,
        __bf16* __restrict__ Hhi, __bf16* __restrict__ Hlo,
        float* __restrict__ out3, int m, int count, int store_lo) {
    const int b = blockIdx.x;
    const int w = threadIdx.x >> 6;
    const int lane = threadIdx.x & 63;
    const int lr = lane & 15;
    const int quad = lane >> 4;

    if (b < count) {
        const __bf16* Ahi = Hhi + (size_t)b * C * S;
        const __bf16* Alo = Hlo + (size_t)b * C * S;
        floatx4 acc[2][2];
#pragma unroll
        for (int mt = 0; mt < 2; mt++)
#pragma unroll
            for (int nt = 0; nt < 2; nt++) acc[mt][nt] = (floatx4)0.f;

#pragma unroll
        for (int kt = 0; kt < 4; kt++) {
            const int ko = kt * 32 + quad * 8;
            const bf16x8 ah0 = *reinterpret_cast<const bf16x8*>(&Ahi[(size_t)lr * S + ko]);
            const bf16x8 ah1 = *reinterpret_cast<const bf16x8*>(&Ahi[(size_t)(16 + lr) * S + ko]);
            const bf16x8 al0 = *reinterpret_cast<const bf16x8*>(&Alo[(size_t)lr * S + ko]);
            const bf16x8 al1 = *reinterpret_cast<const bf16x8*>(&Alo[(size_t)(16 + lr) * S + ko]);
            const bf16x8 bh0 = *reinterpret_cast<const bf16x8*>(&Thi[(size_t)(w * 32 + lr) * S + ko]);
            const bf16x8 bh1 = *reinterpret_cast<const bf16x8*>(&Thi[(size_t)(w * 32 + 16 + lr) * S + ko]);
            const bf16x8 bl0 = *reinterpret_cast<const bf16x8*>(&Tlo[(size_t)(w * 32 + lr) * S + ko]);
            const bf16x8 bl1 = *reinterpret_cast<const bf16x8*>(&Tlo[(size_t)(w * 32 + 16 + lr) * S + ko]);
            acc[0][0] = __builtin_amdgcn_mfma_f32_16x16x32_bf16(ah0, bh0, acc[0][0], 0, 0, 0);
            acc[0][0] = __builtin_amdgcn_mfma_f32_16x16x32_bf16(ah0, bl0, acc[0][0], 0, 0, 0);
            acc[0][0] = __builtin_amdgcn_mfma_f32_16x16x32_bf16(al0, bh0, acc[0][0], 0, 0, 0);
            acc[0][1] = __builtin_amdgcn_mfma_f32_16x16x32_bf16(ah0, bh1, acc[0][1], 0, 0, 0);
            acc[0][1] = __builtin_amdgcn_mfma_f32_16x16x32_bf16(ah0, bl1, acc[0][1], 0, 0, 0);
            acc[0][1] = __builtin_amdgcn_mfma_f32_16x16x32_bf16(al0, bh1, acc[0][1], 0, 0, 0);
            acc[1][0] = __builtin_amdgcn_mfma_f32_16x16x32_bf16(ah1, bh0, acc[1][0], 0, 0, 0);
            acc[1][0] = __builtin_amdgcn_mfma_f32_16x16x32_bf16(ah1, bl0, acc[1][0], 0, 0, 0);
            acc[1][0] = __builtin_amdgcn_mfma_f32_16x16x32_bf16(al1, bh0, acc[1][0], 0, 0, 0);
            acc[1][1] = __builtin_amdgcn_mfma_f32_16x16x32_bf16(ah1, bh1, acc[1][1], 0, 0, 0);
            acc[1][1] = __builtin_amdgcn_mfma_f32_16x16x32_bf16(ah1, bl1, acc[1][1], 0, 0, 0);
            acc[1][1] = __builtin_amdgcn_mfma_f32_16x16x32_bf16(al1, bh1, acc[1][1], 0, 0, 0);
        }

        const size_t t = (size_t)m + b;
#pragma unroll
        for (int mt = 0; mt < 2; mt++) {
#pragma unroll
            for (int nt = 0; nt < 2; nt++) {
#pragma unroll
                for (int reg = 0; reg < 4; reg++) {
                    const int c = mt * 16 + quad * 4 + reg;
                    const int n = w * 32 + nt * 16 + lr;
                    const float p = acc[mt][nt][reg];
                    __bf16 hi, lo; split_bf16(p, hi, lo);
                    Hhi[(t * C + c) * S + n] = hi;
                    if (store_lo) Hlo[(t * C + c) * S + n] = lo;
                    out3[(t * C + c) * S + n] = __logf(p);
                }
            }
        }
    } else {
        const int rb = b - count;
        floatx4 acc[2];
        acc[0] = (floatx4)0.f; acc[1] = (floatx4)0.f;
#pragma unroll
        for (int kt = 0; kt < 4; kt++) {
            const int ko = kt * 32 + quad * 8;
            const bf16x8 ah = *reinterpret_cast<const bf16x8*>(&Rhi[(size_t)(rb * 16 + lr) * S + ko]);
            const bf16x8 al = *reinterpret_cast<const bf16x8*>(&Rlo[(size_t)(rb * 16 + lr) * S + ko]);
            const bf16x8 bh0 = *reinterpret_cast<const bf16x8*>(&Thi[(size_t)(w * 32 + lr) * S + ko]);
            const bf16x8 bh1 = *reinterpret_cast<const bf16x8*>(&Thi[(size_t)(w * 32 + 16 + lr) * S + ko]);
            const bf16x8 bl0 = *reinterpret_cast<const bf16x8*>(&Tlo[(size_t)(w * 32 + lr) * S + ko]);
            const bf16x8 bl1 = *reinterpret_cast<const bf16x8*>(&Tlo[(size_t)(w * 32 + 16 + lr) * S + ko]);
            acc[0] = __builtin_amdgcn_mfma_f32_16x16x32_bf16(ah, bh0, acc[0], 0, 0, 0);
            acc[0] = __builtin_amdgcn_mfma_f32_16x16x32_bf16(ah, bl0, acc[0], 0, 0, 0);
            acc[0] = __builtin_amdgcn_mfma_f32_16x16x32_bf16(al, bh0, acc[0], 0, 0, 0);
            acc[1] = __builtin_amdgcn_mfma_f32_16x16x32_bf16(ah, bh1, acc[1], 0, 0, 0);
            acc[1] = __builtin_amdgcn_mfma_f32_16x16x32_bf16(ah, bl1, acc[1], 0, 0, 0);
            acc[1] = __builtin_amdgcn_mfma_f32_16x16x32_bf16(al, bh1, acc[1], 0, 0, 0);
        }
#pragma unroll
        for (int nt = 0; nt < 2; nt++) {
#pragma unroll
            for (int reg = 0; reg < 4; reg++) {
                const int row = rb * 16 + quad * 4 + reg;
                const int col = w * 32 + nt * 16 + lr;
                const float p = acc[nt][reg];
                __bf16 hi, lo; split_bf16(p, hi, lo);
                Rnhi[(size_t)row * S + col] = hi; Rnlo[(size_t)row * S + col] = lo;
                Tnhi[(size_t)col * S + row] = hi; Tnlo[(size_t)col * S + row] = lo;
            }
        }
    }
}

// ---------------------------------------------------------------------------
// Observation GEMM (R6-proven): t-batched, LDS-shared B, 512 threads.
// Block covers 128 n-cols x 8 t's; pET tile staged once in LDS and reused
// across 8 waves / 8 t's. Diagnostic round established this kernel runs at
// <=90 us full-grid vs a ~74 us traffic roofline -- near-floor.
// ---------------------------------------------------------------------------
__global__ __launch_bounds__(512, 4) void obs_mfma_kernel(
        const __bf16* __restrict__ Hb,    // [T,C,S] (hi plane)
        const __bf16* __restrict__ pET,   // [N,S]
        const float* __restrict__ pcw,    // [T,C]
        float* __restrict__ out1,
        float* __restrict__ out2) {
    constexpr int BPITCH = 264;  // bytes per LDS row (256 data + 8 pad)
    __shared__ __align__(16) unsigned char Bs[128 * BPITCH];  // 33 KB
    __shared__ float sw[8][C];

    const int tid = threadIdx.x;
    const int w = tid >> 6;
    const int lane = tid & 63;
    const int l31 = lane & 31;
    const int half = lane >> 5;
    const int nw = (w & 1) * 64;       // wave's n-half within block
    const int tg = w >> 1;             // wave's t-pair index (0..3)
    const int nblk = blockIdx.x * 128;
    const int tbase = blockIdx.y * 8;
    const int t0 = tbase + tg * 2;
    const int t1 = t0 + 1;

    // Stage pET rows [nblk, nblk+128) into LDS (padded pitch, coalesced 16B).
#pragma unroll
    for (int p = 0; p < 4; p++) {
        const int idx = p * 512 + tid;     // 0..2047
        const int row = idx >> 4;          // 0..127
        const int c16 = idx & 15;          // 16B chunk within row
        const float4 v = *reinterpret_cast<const float4*>(
            pET + (size_t)(nblk + row) * S + c16 * 8);
        *reinterpret_cast<float4*>(Bs + row * BPITCH + c16 * 16) = v;
    }
    if (tid < 256) sw[tid >> 5][tid & 31] =
        pcw[(size_t)(tbase + (tid >> 5)) * C + (tid & 31)];
    __syncthreads();

    const __bf16* A0 = Hb + (size_t)t0 * C * S;
    const __bf16* A1 = Hb + (size_t)t1 * C * S;

    floatx16 acc[2][2];   // [t][ntile]
#pragma unroll
    for (int tt = 0; tt < 2; tt++)
#pragma unroll
        for (int nt = 0; nt < 2; nt++) acc[tt][nt] = (floatx16)0.f;

#pragma unroll
    for (int ks = 0; ks < 8; ks++) {
        const int ko = ks * 16 + half * 8;
        const bf16x8 a0 = *reinterpret_cast<const bf16x8*>(&A0[(size_t)l31 * S + ko]);
        const bf16x8 a1 = *reinterpret_cast<const bf16x8*>(&A1[(size_t)l31 * S + ko]);
        const bf16x8 b0 = *reinterpret_cast<const bf16x8*>(Bs + (nw + l31) * BPITCH + ko * 2);
        const bf16x8 b1 = *reinterpret_cast<const bf16x8*>(Bs + (nw + 32 + l31) * BPITCH + ko * 2);
        acc[0][0] = __builtin_amdgcn_mfma_f32_32x32x16_bf16(a0, b0, acc[0][0], 0, 0, 0);
        acc[0][1] = __builtin_amdgcn_mfma_f32_32x32x16_bf16(a0, b1, acc[0][1], 0, 0, 0);
        acc[1][0] = __builtin_amdgcn_mfma_f32_32x32x16_bf16(a1, b0, acc[1][0], 0, 0, 0);
        acc[1][1] = __builtin_amdgcn_mfma_f32_32x32x16_bf16(a1, b1, acc[1][1], 0, 0, 0);
    }

#pragma unroll
    for (int tt = 0; tt < 2; tt++) {
        const int t = t0 + tt;
        float p0 = 0.f, p1 = 0.f;
#pragma unroll
        for (int reg = 0; reg < 16; reg++) {
            const int c = (reg & 3) + 8 * (reg >> 2) + 4 * half;
            const float o0 = acc[tt][0][reg];
            const float o1 = acc[tt][1][reg];
            __builtin_nontemporal_store(__logf(o0),
                &out2[((size_t)t * C + c) * N + nblk + nw + l31]);
            __builtin_nontemporal_store(__logf(o1),
                &out2[((size_t)t * C + c) * N + nblk + nw + 32 + l31]);
            p0 = fmaf(sw[tg * 2 + tt][c], o0, p0);
            p1 = fmaf(sw[tg * 2 + tt][c], o1, p1);
        }
        p0 += __shfl_xor(p0, 32, 64);
        p1 += __shfl_xor(p1, 32, 64);
        if (half == 0) {
            __builtin_nontemporal_store(__logf(p0), &out1[(size_t)t * N + nblk + nw + l31]);
            __builtin_nontemporal_store(__logf(p1), &out1[(size_t)t * N + nblk + nw + 32 + l31]);
        }
    }
}

// ---------------------------------------------------------------------------
extern "C" void kernel_launch(void* const* d_in, const int* in_sizes, int n_in,
                              void* d_out, int out_size, void* d_ws, size_t ws_size,
                              hipStream_t stream) {
    const float* in_init  = (const float*)d_in[0];  // [C,S]
    const float* in_cw    = (const float*)d_in[1];  // [T,C]
    const float* in_emis  = (const float*)d_in[2];  // [S,N]
    const float* in_trans = (const float*)d_in[3];  // [S,S]

    float* out = (float*)d_out;

    // Workspace layout (~9.5 MB, 256B aligned)
    char* wsb = (char*)d_ws;
    float*  ws_pcw = (float*)(wsb);                                  // 64 KB [T,C]
    __bf16* ws_pET = (__bf16*)(wsb + (64u << 10));                   // 1 MB  [N,S]
    __bf16* ws_Hhi = (__bf16*)(wsb + (1088u << 10));                 // 4 MB  [T,C,S]
    __bf16* ws_Hlo = (__bf16*)(wsb + (5184u << 10));                 // 4 MB  [T,C,S]
    __bf16* Pslot[2][4];
    for (int sl = 0; sl < 2; sl++)
        for (int pl = 0; pl < 4; pl++)
            Pslot[sl][pl] = (__bf16*)(wsb + (9280u << 10) + (size_t)(sl * 4 + pl) * (32u << 10));

    // 1) All softmaxes in one launch.
    fused_softmax_kernel<<<352, 256, 0, stream>>>(
        in_emis, in_cw, in_trans, in_init,
        out + OFF3, out + OFF4, out + OFF5,
        ws_pET, ws_pcw,
        Pslot[0][0], Pslot[0][1], Pslot[0][2], Pslot[0][3],
        ws_Hhi, ws_Hlo);

    // 2) H-doubling rounds (hi/lo-pair MFMA), 9 separate launches (proven).
    //    r=9 outputs (t>=256) are never A-inputs -> skip their lo stores.
    for (int r = 1; r <= 9; r++) {
        const int m = 1 << (r - 1);
        const int count = (m < T - m) ? m : (T - m);
        const int s = (r - 1) & 1, d = r & 1;
        const int extra = (r < 9) ? 8 : 0;
        h_round_kernel<<<count + extra, 256, 0, stream>>>(
            Pslot[s][0], Pslot[s][1], Pslot[s][2], Pslot[s][3],
            Pslot[d][0], Pslot[d][1], Pslot[d][2], Pslot[d][3],
            ws_Hhi, ws_Hlo, out + OFF3, m, count, (r < 9) ? 1 : 0);
    }

    // 3) Observation GEMM (R6-proven grid).
    obs_mfma_kernel<<<dim3(N / 128, T / 8), 512, 0, stream>>>(
        ws_Hhi, ws_pET, ws_pcw, out + OFF1, out + OFF2);
}